// Round 6
// baseline (147.477 us; speedup 1.0000x reference)
//
#include <hip/hip_runtime.h>

typedef unsigned short u16;
typedef unsigned int u32;
using frag8 = __attribute__((ext_vector_type(8))) short;  // 8 bf16 (4 VGPRs)
using f32x4 = __attribute__((ext_vector_type(4))) float;

#define MFMA(a, b, c) __builtin_amdgcn_mfma_f32_16x16x32_bf16(a, b, c, 0, 0, 0)

// fp32 -> bf16, round-to-nearest-even (finite inputs only)
__device__ __forceinline__ u16 f2bf(float f) {
  u32 x = __float_as_uint(f);
  x += 0x7fffu + ((x >> 16) & 1u);
  return (u16)(x >> 16);
}

// ---------------------------------------------------------------------------
// Pre-pass: qkv (4,1536,2048) fp32 ->
//   Qt[b][t][c] bf16 (scaled), Kt[b][s][c] bf16 (scaled), Vn[b][c][s] bf16
// Q,K pre-scaled by 64^-0.25 * sqrt(log2 e) so the flash kernel uses raw
// v_exp_f32.
// ---------------------------------------------------------------------------
__global__ __launch_bounds__(256) void qkv_prepass_kernel(
    const float* __restrict__ qkv, u16* __restrict__ Qt, u16* __restrict__ Kt,
    u16* __restrict__ Vn) {
  __shared__ float tile[64 * 65];
  const int id = blockIdx.x;
  const int tid = threadIdx.x;

  if (id < 2048) {
    const bool isK = id >= 1024;
    const int lid = isK ? (id - 1024) : id;
    const int b = lid >> 5;
    const int t0 = (lid & 31) * 64;
    const int bs = b >> 3, h = b & 7;
    const float* src =
        qkv + ((size_t)(bs * 1536 + h * 192 + (isK ? 64 : 0))) * 2048 + t0;
    u16* dst = (isK ? Kt : Qt) + ((size_t)b * 2048 + t0) * 64;
    const float scale = 0.42466090014400953f;  // 64^-0.25 * sqrt(log2 e)

    const int t4 = (tid & 15) * 4;
    const int c = tid >> 4;
#pragma unroll
    for (int i = 0; i < 4; ++i) {
      int cc = c + 16 * i;
      float4 f = *reinterpret_cast<const float4*>(src + (size_t)cc * 2048 + t4);
      tile[cc * 65 + t4 + 0] = f.x * scale;
      tile[cc * 65 + t4 + 1] = f.y * scale;
      tile[cc * 65 + t4 + 2] = f.z * scale;
      tile[cc * 65 + t4 + 3] = f.w * scale;
    }
    __syncthreads();
    const int c0 = (tid & 7) * 8;
#pragma unroll
    for (int p = 0; p < 2; ++p) {
      int tr = (tid >> 3) + 32 * p;
      u32 pk[4];
#pragma unroll
      for (int uu = 0; uu < 4; ++uu) {
        u16 lo = f2bf(tile[(c0 + 2 * uu) * 65 + tr]);
        u16 hi = f2bf(tile[(c0 + 2 * uu + 1) * 65 + tr]);
        pk[uu] = (u32)lo | ((u32)hi << 16);
      }
      *reinterpret_cast<uint4*>(dst + (size_t)tr * 64 + c0) =
          make_uint4(pk[0], pk[1], pk[2], pk[3]);
    }
  } else {
    const size_t base = (size_t)(id - 2048) * 4096;
#pragma unroll
    for (int it = 0; it < 2; ++it) {
      size_t vi = base + (size_t)it * 2048 + (size_t)tid * 8;
      int b = (int)(vi >> 17);
      int r = (int)(vi & 131071);
      int bs = b >> 3, h = b & 7;
      const float* sp = qkv + ((size_t)(bs * 1536 + h * 192 + 128)) * 2048 + r;
      float4 f0 = *reinterpret_cast<const float4*>(sp);
      float4 f1 = *reinterpret_cast<const float4*>(sp + 4);
      uint4 pk;
      pk.x = (u32)f2bf(f0.x) | ((u32)f2bf(f0.y) << 16);
      pk.y = (u32)f2bf(f0.z) | ((u32)f2bf(f0.w) << 16);
      pk.z = (u32)f2bf(f1.x) | ((u32)f2bf(f1.y) << 16);
      pk.w = (u32)f2bf(f1.z) | ((u32)f2bf(f1.w) << 16);
      *reinterpret_cast<uint4*>(Vn + vi) = pk;
    }
  }
}

// ---------------------------------------------------------------------------
// Flash attention, S^T form, no-max softmax, skewed pipeline, 64 t PER WAVE:
// each K/V fragment read now feeds 4 MFMAs (was 2) -> LDS-read traffic per
// output halved (LDS pipe was ~66% busy, the R5 limiter).
// Block = 256 thr (4 waves x 64 t = 256 t), grid 256 (1 block/CU, XCD-swizz).
// LDS (u16 units): QP overlay [0,16384) | K dbuf @16384+ks*4096 |
//                  V dbuf @24576+vs*4096  = 64 KiB. XOR-swizzled 64x64 tiles.
// Slot schedule: body k reads K slot (k+1)&1 (S_{k+1}) + V slot k&1 (PV_k),
// stages K_{k+2}->slot k&1, V_{k+1}->slot (k+1)&1; one barrier per body.
// ---------------------------------------------------------------------------
#define STAGE(dstOff, srcPtr)                                                  \
  __builtin_amdgcn_global_load_lds(                                            \
      (const __attribute__((address_space(1))) void*)(srcPtr),                 \
      (__attribute__((address_space(3))) void*)(ldsbase + (dstOff) + tid * 8), \
      16, 0, 0)

#define STG_K(KT, KS)                                                       \
  STAGE(16384 + (KS) * 4096, Kg + (size_t)(KT) * 4096 + koff0);             \
  STAGE(16384 + (KS) * 4096 + 2048, Kg + (size_t)(KT) * 4096 + koff0 + 2048);

#define STG_V(VT, VS)                                                       \
  STAGE(24576 + (VS) * 4096, Vg + (size_t)(VT) * 64 + voff0);               \
  STAGE(24576 + (VS) * 4096 + 2048, Vg + (size_t)(VT) * 64 + voff0 + 65536);

#define EXPP(SC)                                                            \
  _Pragma("unroll") for (int j = 0; j < 4; ++j) {                           \
    _Pragma("unroll") for (int i = 0; i < 4; ++i) {                         \
      float p0 = __builtin_amdgcn_exp2f(SC[i][j][0]);                       \
      float p1 = __builtin_amdgcn_exp2f(SC[i][j][1]);                       \
      float p2 = __builtin_amdgcn_exp2f(SC[i][j][2]);                       \
      float p3 = __builtin_amdgcn_exp2f(SC[i][j][3]);                       \
      lp[j] += (p0 + p1) + (p2 + p3);                                       \
      u32 a0 = __float_as_uint(p0) + 0x8000u;                               \
      u32 a1 = __float_as_uint(p1) + 0x8000u;                               \
      u32 a2 = __float_as_uint(p2) + 0x8000u;                               \
      u32 a3 = __float_as_uint(p3) + 0x8000u;                               \
      *(uint2*)(pwb + j * 1024 + pslot[i]) =                                \
          make_uint2(__builtin_amdgcn_perm(a1, a0, 0x07060302u),            \
                     __builtin_amdgcn_perm(a3, a2, 0x07060302u));           \
    }                                                                       \
  }

#define PVACC(VCS)                                                          \
  {                                                                         \
    frag8 aP0[4], aP1[4];                                                   \
    _Pragma("unroll") for (int j = 0; j < 4; ++j) {                         \
      aP0[j] = *(const frag8*)(pqb + j * 1024 + off0);                      \
      aP1[j] = *(const frag8*)(pqb + j * 1024 + off1);                      \
    }                                                                       \
    _Pragma("unroll") for (int i = 0; i < 4; ++i) {                         \
      const frag8 v0 = *(const frag8*)(vA + (VCS) * 4096 + i * 1024);       \
      const frag8 v1 = *(const frag8*)(vB + (VCS) * 4096 + i * 1024);       \
      _Pragma("unroll") for (int j = 0; j < 4; ++j) {                       \
        o[i][j] = MFMA(v0, aP0[j], o[i][j]);                                \
        o[i][j] = MFMA(v1, aP1[j], o[i][j]);                                \
      }                                                                     \
    }                                                                       \
  }

// body k: stage ahead; compute S_{k+1} (K-frag reads + MFMA, independent
// chain); exp/P-write of S_k; fence; P-read + PV of tile k; barrier.
#define BODY(NXS, VCS, SC, SN, STG)                                         \
  {                                                                         \
    STG                                                                     \
    _Pragma("unroll") for (int i = 0; i < 4; ++i) {                         \
      const frag8 k0 = *(const frag8*)(rdA + (NXS) * 4096 + i * 1024);      \
      const frag8 k1 = *(const frag8*)(rdB + (NXS) * 4096 + i * 1024);      \
      _Pragma("unroll") for (int j = 0; j < 4; ++j) {                       \
        f32x4 z = {0.f, 0.f, 0.f, 0.f};                                     \
        z = MFMA(k0, aQ0[j], z);                                            \
        z = MFMA(k1, aQ1[j], z);                                            \
        SN[i][j] = z;                                                       \
      }                                                                     \
    }                                                                       \
    EXPP(SC)                                                                \
    asm volatile("" ::: "memory"); /* P-writes before P-reads */            \
    PVACC(VCS)                                                              \
    __syncthreads();                                                        \
  }

__global__ __launch_bounds__(256, 1) void attn_flash_kernel(
    const u16* __restrict__ Qt, const u16* __restrict__ Kt,
    const u16* __restrict__ Vn, float* __restrict__ out) {
  __shared__ __align__(16) unsigned char smem[65536];
  u16* ldsbase = (u16*)smem;

  // XCD swizzle: blk&7 = XCD; 4 heads per XCD -> K/V L2-resident per XCD
  const int blk = blockIdx.x;
  const int ii = blk >> 3;
  const int b = ((blk & 7) << 2) + (ii >> 3);  // head 0..31
  const int qt = ii & 7;                       // q-tile (256 t each)

  const int tid = threadIdx.x;
  const int w = tid >> 6;  // wave -> t-range [64w, 64w+64)
  const int lane = tid & 63;
  const int s16 = lane & 15, q = lane >> 4;
  const int x = s16 & 7;

  const u16* Qg = Qt + ((size_t)b * 2048 + qt * 256) * 64;
  const u16* Kg = Kt + (size_t)b * 2048 * 64;
  const u16* Vg = Vn + (size_t)b * 64 * 2048;

  // staging lane offsets (u16 units)
  const int srow = tid >> 3;
  const int sgl = (tid & 7) ^ (srow & 7);
  const int koff0 = srow * 64 + sgl * 8;    // pitch-64 tiles (Q,K)
  const int voff0 = srow * 2048 + sgl * 8;  // pitch-2048 (V)

  // fragment read bases (swizzled; +i*1024 per 16-row chunk via imm)
  const u16* rdA = ldsbase + 16384 + s16 * 64 + ((q ^ x) * 8);
  const u16* rdB = ldsbase + 16384 + s16 * 64 + (((q + 4) ^ x) * 8);
  const u16* vA = ldsbase + 24576 + s16 * 64 + ((q ^ x) * 8);
  const u16* vB = ldsbase + 24576 + s16 * 64 + (((q + 4) ^ x) * 8);
  // Q/P row base for this wave (chunk j at +j*1024); row&7 == x for all j
  const u16* pqb = ldsbase + (w * 64 + s16) * 64;
  u16* pwb = (u16*)pqb;
  const int off0 = (q ^ x) * 8;
  const int off1 = ((q + 4) ^ x) * 8;
  int pslot[4];
#pragma unroll
  for (int i = 0; i < 4; ++i)
    pslot[i] = ((2 * i + (q >> 1)) ^ x) * 8 + (q & 1) * 4;

  // prologue: stage Q (256x64 = 8 ops), K0->slot0, K1->slot1, V0->slot0
  STAGE(0, Qg + koff0);
  STAGE(2048, Qg + koff0 + 2048);
  STAGE(4096, Qg + koff0 + 4096);
  STAGE(6144, Qg + koff0 + 6144);
  STAGE(8192, Qg + koff0 + 8192);
  STAGE(10240, Qg + koff0 + 10240);
  STAGE(12288, Qg + koff0 + 12288);
  STAGE(14336, Qg + koff0 + 14336);
  STG_K(0, 0)
  STG_K(1, 1)
  STG_V(0, 0)
  __syncthreads();

  // loop-invariant Q fragments; QP region then becomes P (wave-private rows)
  frag8 aQ0[4], aQ1[4];
#pragma unroll
  for (int j = 0; j < 4; ++j) {
    aQ0[j] = *(const frag8*)(pqb + j * 1024 + off0);
    aQ1[j] = *(const frag8*)(pqb + j * 1024 + off1);
  }

  f32x4 o[4][4];
#pragma unroll
  for (int i = 0; i < 4; ++i)
#pragma unroll
    for (int j = 0; j < 4; ++j) o[i][j] = (f32x4){0.f, 0.f, 0.f, 0.f};
  float lp[4] = {0.f, 0.f, 0.f, 0.f};

  // S_0 from K slot 0 -> sA
  f32x4 sA[4][4], sB[4][4];
#pragma unroll
  for (int i = 0; i < 4; ++i) {
    const frag8 k0 = *(const frag8*)(rdA + i * 1024);
    const frag8 k1 = *(const frag8*)(rdB + i * 1024);
#pragma unroll
    for (int j = 0; j < 4; ++j) {
      f32x4 z = {0.f, 0.f, 0.f, 0.f};
      z = MFMA(k0, aQ0[j], z);
      z = MFMA(k1, aQ1[j], z);
      sA[i][j] = z;
    }
  }

  // pipeline: body k consumes S_k, produces S_{k+1}
  for (int kt = 0; kt < 30; kt += 2) {
    BODY(1, 0, sA, sB, STG_K(kt + 2, 0) STG_V(kt + 1, 1))  // k=kt   (even)
    BODY(0, 1, sB, sA, STG_K(kt + 3, 1) STG_V(kt + 2, 0))  // k=kt+1 (odd)
  }
  BODY(1, 0, sA, sB, STG_V(31, 1))  // k=30: S_31 from slot 1, V30 slot 0

  // tail: exp/PV of tile 31 (S in sB, V in slot 1)
  {
    EXPP(sB)
    asm volatile("" ::: "memory");
    PVACC(1)
  }

  // softmax denominators: cross-quad reduce (lanes share t = s16)
  float rl[4];
#pragma unroll
  for (int j = 0; j < 4; ++j) {
    lp[j] += __shfl_xor(lp[j], 16);
    lp[j] += __shfl_xor(lp[j], 32);
    rl[j] = 1.0f / lp[j];
  }

  // lane holds O^T[c = i*16 + q*4 + r][t = qt*256 + 64w + 16j + s16]
  float* ob = out + (size_t)(b * 64 + q * 4) * 2048 + qt * 256 + w * 64 + s16;
#pragma unroll
  for (int i = 0; i < 4; ++i)
#pragma unroll
    for (int j = 0; j < 4; ++j)
#pragma unroll
      for (int r = 0; r < 4; ++r)
        ob[(size_t)(i * 16 + r) * 2048 + j * 16] = o[i][j][r] * rl[j];
}

extern "C" void kernel_launch(void* const* d_in, const int* in_sizes, int n_in,
                              void* d_out, int out_size, void* d_ws,
                              size_t ws_size, hipStream_t stream) {
  const float* qkv = (const float*)d_in[0];
  float* out = (float*)d_out;
  u16* Qt = (u16*)d_ws;
  u16* Kt = Qt + (size_t)32 * 2048 * 64;
  u16* Vn = Kt + (size_t)32 * 2048 * 64;

  qkv_prepass_kernel<<<3072, 256, 0, stream>>>(qkv, Qt, Kt, Vn);
  attn_flash_kernel<<<256, 256, 0, stream>>>(Qt, Kt, Vn, out);
}